// Round 4
// baseline (3541.011 us; speedup 1.0000x reference)
//
#include <hip/hip_runtime.h>
#include <math.h>

typedef _Float16 h2 __attribute__((ext_vector_type(2)));
typedef _Float16 h8 __attribute__((ext_vector_type(8)));

__device__ __forceinline__ float sigmf_(float x){ return 1.0f/(1.0f + expf(-x)); }

// ---------------- P1/P3: C[1024][1536] = A[1024][K] @ [Wf;Wb]^T + [bf;bb] ----
template<bool GATHER, int K>
__global__ __launch_bounds__(256)
void gi_gemm(const float* __restrict__ A, const int* __restrict__ xids,
             const float* __restrict__ emb,
             const float* __restrict__ Wf, const float* __restrict__ Wb,
             const float* __restrict__ bf, const float* __restrict__ bb,
             float* __restrict__ C)
{
  __shared__ float As[64][17];
  __shared__ float Bs[64][17];
  __shared__ int xs[64];
  const int tid = threadIdx.x;
  const int m0 = blockIdx.x*64, n0 = blockIdx.y*64;
  if (GATHER && tid < 64) xs[tid] = xids[m0+tid];
  __syncthreads();
  const int tx = tid & 15, ty = tid >> 4;
  float acc[4][4] = {};
  for (int kc = 0; kc < K; kc += 16) {
#pragma unroll
    for (int p = 0; p < 4; ++p) {
      int r = ty + 16*p;
      float av;
      if (GATHER) av = emb[(size_t)xs[r]*K + kc + tx];
      else        av = A[(size_t)(m0+r)*K + kc + tx];
      As[r][tx] = av;
      int cn = n0 + r;
      float bv = (cn < 768) ? Wf[(size_t)cn*K + kc + tx]
                            : Wb[(size_t)(cn-768)*K + kc + tx];
      Bs[r][tx] = bv;
    }
    __syncthreads();
#pragma unroll
    for (int kk = 0; kk < 16; ++kk) {
      float a0=As[ty*4+0][kk], a1=As[ty*4+1][kk], a2=As[ty*4+2][kk], a3=As[ty*4+3][kk];
      float b0=Bs[tx*4+0][kk], b1=Bs[tx*4+1][kk], b2=Bs[tx*4+2][kk], b3=Bs[tx*4+3][kk];
      acc[0][0]+=a0*b0; acc[0][1]+=a0*b1; acc[0][2]+=a0*b2; acc[0][3]+=a0*b3;
      acc[1][0]+=a1*b0; acc[1][1]+=a1*b1; acc[1][2]+=a1*b2; acc[1][3]+=a1*b3;
      acc[2][0]+=a2*b0; acc[2][1]+=a2*b1; acc[2][2]+=a2*b2; acc[2][3]+=a2*b3;
      acc[3][0]+=a3*b0; acc[3][1]+=a3*b1; acc[3][2]+=a3*b2; acc[3][3]+=a3*b3;
    }
    __syncthreads();
  }
#pragma unroll
  for (int i=0;i<4;++i)
#pragma unroll
    for (int jj=0;jj<4;++jj) {
      int col = n0 + tx*4 + jj;
      float bias = (col<768)? bf[col] : bb[col-768];
      C[(size_t)(m0+ty*4+i)*1536 + col] = acc[i][jj] + bias;
    }
}

// ---------------- Sequential GRU layer: 2 blocks (cell f/b) x 1024 threads ----
// Thread (j,q): j = tid>>2 owns h-element j; q = tid&3 owns column quarter
// [q*64, q*64+64) of gate rows {j, j+256, j+512}. Weights = 3*32 h2 = 96 VGPRs
// per thread -> total ~126 live regs, fits the 128-reg budget the allocator
// picks (prior rounds: at 192 weight regs it rematerialized the weight loads
// + cvts inside the loop -> 4x VALU). waves_per_eu(4,4) pins the target.
template<int LAYER>
__global__ __launch_bounds__(1024, 1) __attribute__((amdgpu_waves_per_eu(4, 4)))
void enc_recur(const float* __restrict__ G,      // [1024][1536] gi (incl bih)
               const float* __restrict__ WhhF, const float* __restrict__ WhhB,
               const float* __restrict__ bhhF, const float* __restrict__ bhhB,
               const float* __restrict__ eh0,   // [4][256]
               float* __restrict__ outbuf,      // [1024][512]
               float* __restrict__ dh)          // [512]
{
  const int c = blockIdx.x;       // 0 = f, 1 = b
  const int tid = threadIdx.x;
  const int j = tid >> 2, q = tid & 3;
  const float* __restrict__ Whh = c ? WhhB : WhhF;
  const float* __restrict__ bhh = c ? bhhB : bhhF;
  // chunk q at f16 offset q*72 (144 B): chunks start on banks 0,4,8,12
  __shared__ __align__(16) _Float16 hh[2][288];

  h2 w0[32], w1[32], w2[32];
  {
    const float* r0 = Whh + (size_t)( j      )*256 + q*64;
    const float* r1 = Whh + (size_t)( j+256  )*256 + q*64;
    const float* r2 = Whh + (size_t)( j+512  )*256 + q*64;
#pragma unroll
    for (int k = 0; k < 32; ++k) {
      w0[k] = h2{(_Float16)r0[2*k], (_Float16)r0[2*k+1]};
      w1[k] = h2{(_Float16)r1[2*k], (_Float16)r1[2*k+1]};
      w2[k] = h2{(_Float16)r2[2*k], (_Float16)r2[2*k+1]};
    }
  }
  // bias folded into q==0's accumulator so the quad-sum adds it exactly once
  const float br = q ? 0.0f : bhh[j];
  const float bz = q ? 0.0f : bhh[j+256];
  const float bn = q ? 0.0f : bhh[j+512];
  float h = eh0[(LAYER*2 + c)*256 + j];
  if (q == 0) hh[0][(j>>6)*72 + (j&63)] = (_Float16)h;
  __syncthreads();

  const float* Gn = G + c*768 + j;          // row t per-thread base
  float gr = Gn[0], gz = Gn[256], gn_ = Gn[512];
  float* ob = outbuf + c*256 + j;

  for (int t = 0; t < 1024; ++t) {
    // prefetch next row's gi (t=1023 reads one row past G -> lands in the
    // adjacent ws buffer, value unused)
    Gn += 1536;
    float pr = Gn[0], pz = Gn[256], pn = Gn[512];

    float ar = br, az = bz, an = bn;
    const h8* __restrict__ hb = (const h8*)(hh[t & 1] + q*72);
#pragma unroll
    for (int kk = 0; kk < 8; ++kk) {
      h8 hv = hb[kk];
      h2 p0 = h2{hv[0],hv[1]}, p1 = h2{hv[2],hv[3]};
      h2 p2 = h2{hv[4],hv[5]}, p3 = h2{hv[6],hv[7]};
      ar = __builtin_amdgcn_fdot2(w0[4*kk+0], p0, ar, false);
      az = __builtin_amdgcn_fdot2(w1[4*kk+0], p0, az, false);
      an = __builtin_amdgcn_fdot2(w2[4*kk+0], p0, an, false);
      ar = __builtin_amdgcn_fdot2(w0[4*kk+1], p1, ar, false);
      az = __builtin_amdgcn_fdot2(w1[4*kk+1], p1, az, false);
      an = __builtin_amdgcn_fdot2(w2[4*kk+1], p1, an, false);
      ar = __builtin_amdgcn_fdot2(w0[4*kk+2], p2, ar, false);
      az = __builtin_amdgcn_fdot2(w1[4*kk+2], p2, az, false);
      an = __builtin_amdgcn_fdot2(w2[4*kk+2], p2, an, false);
      ar = __builtin_amdgcn_fdot2(w0[4*kk+3], p3, ar, false);
      az = __builtin_amdgcn_fdot2(w1[4*kk+3], p3, az, false);
      an = __builtin_amdgcn_fdot2(w2[4*kk+3], p3, an, false);
    }
    // combine the four column-quarters (quad-local butterfly)
    ar += __shfl_xor(ar, 1); ar += __shfl_xor(ar, 2);
    az += __shfl_xor(az, 1); az += __shfl_xor(az, 2);
    an += __shfl_xor(an, 1); an += __shfl_xor(an, 2);

    float r = sigmf_(gr + ar);
    float z = sigmf_(gz + az);
    float n = tanhf(gn_ + r*an);
    h = (1.0f - z)*n + z*h;
    if (q == 0) {
      ob[0] = h; ob += 512;
      hh[(t+1) & 1][(j>>6)*72 + (j&63)] = (_Float16)h;  // other buffer: no WAR
    }
    gr = pr; gz = pz; gn_ = pn;
    __syncthreads();                    // writes visible before next step reads
  }
  if (LAYER == 0 && c == 0 && q == 0) dh[j] = h;         // dh = concat(h0f, h1b)
  if (LAYER == 1 && c == 1 && q == 0) dh[256 + j] = h;
}

// ---------------- row-wise log_softmax over 512 features ----------------
__global__ __launch_bounds__(256)
void row_logsoftmax(const float* __restrict__ in, float* __restrict__ outp)
{
  const int t = blockIdx.x, i = threadIdx.x;
  __shared__ float red[256];
  float v0 = in[(size_t)t*512 + i], v1 = in[(size_t)t*512 + 256 + i];
  red[i] = fmaxf(v0, v1); __syncthreads();
  for (int s = 128; s > 0; s >>= 1) { if (i < s) red[i] = fmaxf(red[i], red[i+s]); __syncthreads(); }
  float m = red[0]; __syncthreads();
  red[i] = expf(v0-m) + expf(v1-m); __syncthreads();
  for (int s = 128; s > 0; s >>= 1) { if (i < s) red[i] += red[i+s]; __syncthreads(); }
  float ls = m + logf(red[0]);
  outp[(size_t)t*512 + i]       = v0 - ls;
  outp[(size_t)t*512 + 256 + i] = v1 - ls;
}

// ---------------- batched matvec over nd vectors: out[d][r] = act(W[r]·v_d + b[r])
template<int ACT>
__global__ __launch_bounds__(256)
void matvec6(const float* __restrict__ W, const float* __restrict__ bias,
             const float* __restrict__ Va, int strideA, int lenA,
             const float* __restrict__ Vb, int strideB, int lenB,
             int N, float* __restrict__ outp)
{
  const int d = blockIdx.x;
  const int K = lenA + lenB;
  __shared__ float v[1024];
  for (int k = threadIdx.x; k < K; k += 256)
    v[k] = (k < lenA) ? Va[(size_t)d*strideA + k] : Vb[(size_t)d*strideB + (k - lenA)];
  __syncthreads();
  const int tx = threadIdx.x & 15, ty = threadIdx.x >> 4;
  const int r = blockIdx.y*16 + ty;
  if (r < N) {                      // N is always a multiple of 16 here
    float acc = 0.0f;
    for (int k = tx; k < K; k += 16) acc += W[(size_t)r*K + k]*v[k];
    for (int m = 8; m >= 1; m >>= 1) acc += __shfl_xor(acc, m);
    if (tx == 0) {
      acc += bias[r];
      if (ACT == 1) acc = fmaxf(acc, 0.0f);
      outp[(size_t)d*N + r] = acc;
    }
  }
}

// ---------------- softmax over 1024 logits, 6 rows ----------------
__global__ __launch_bounds__(256)
void softmax6(const float* __restrict__ lg, float* __restrict__ aw)
{
  const int d = blockIdx.x, i = threadIdx.x;
  __shared__ float red[256];
  float v[4];
#pragma unroll
  for (int p = 0; p < 4; ++p) v[p] = lg[(size_t)d*1024 + i + 256*p];
  float m = fmaxf(fmaxf(v[0],v[1]), fmaxf(v[2],v[3]));
  red[i] = m; __syncthreads();
  for (int s = 128; s > 0; s >>= 1) { if (i < s) red[i] = fmaxf(red[i], red[i+s]); __syncthreads(); }
  m = red[0]; __syncthreads();
  float e[4]; float sl = 0.0f;
#pragma unroll
  for (int p = 0; p < 4; ++p) { e[p] = expf(v[p]-m); sl += e[p]; }
  red[i] = sl; __syncthreads();
  for (int s = 128; s > 0; s >>= 1) { if (i < s) red[i] += red[i+s]; __syncthreads(); }
  float inv = 1.0f/red[0];
#pragma unroll
  for (int p = 0; p < 4; ++p) aw[(size_t)d*1024 + i + 256*p] = e[p]*inv;
}

// ---------------- ctx[d] = aw[d] @ eoutputs  ([1024]·[1024,512]) ----------------
__global__ __launch_bounds__(256)
void ctx_kernel(const float* __restrict__ aw, const float* __restrict__ eout,
                float* __restrict__ ctx)
{
  const int d = blockIdx.x, c = threadIdx.x;
  __shared__ float a[1024];
  for (int m = c; m < 1024; m += 256) a[m] = aw[(size_t)d*1024 + m];
  __syncthreads();
  float s0 = 0.0f, s1 = 0.0f;
  for (int m = 0; m < 1024; ++m) {
    float am = a[m];
    s0 += am*eout[(size_t)m*512 + c];
    s1 += am*eout[(size_t)m*512 + 256 + c];
  }
  ctx[(size_t)d*512 + c] = s0;
  ctx[(size_t)d*512 + 256 + c] = s1;
}

// ---------------- decoder tail: GRU combine, logits, argmax-chain ----------------
__global__ __launch_bounds__(512)
void dec_final(const float* __restrict__ gidec, const float* __restrict__ ghdec,
               const float* __restrict__ dh, const float* __restrict__ h2tW,
               const float* __restrict__ h2tb,
               float* __restrict__ cseq, float* __restrict__ rs)
{
  __shared__ float hn[6][512];
  __shared__ float t6[36];
  __shared__ float lp0[6];
  __shared__ int amax[6];
  const int i = threadIdx.x;
  for (int d = 0; d < 6; ++d) {
    float r = sigmf_(gidec[(size_t)d*1536 + i]        + ghdec[i]);
    float z = sigmf_(gidec[(size_t)d*1536 + 512 + i]  + ghdec[512 + i]);
    float n = tanhf (gidec[(size_t)d*1536 + 1024 + i] + r*ghdec[1024 + i]);
    hn[d][i] = (1.0f - z)*n + z*dh[i];
  }
  __syncthreads();
  if (i < 36) {
    int d = i/6, k = i%6;
    float acc = h2tb[k];
    for (int q = 0; q < 512; ++q) acc += h2tW[(size_t)k*512 + q]*hn[d][q];
    t6[i] = acc;
  }
  __syncthreads();
  if (i < 6) {
    float m = t6[i*6];
    for (int k = 1; k < 6; ++k) m = fmaxf(m, t6[i*6+k]);
    float s = 0.0f;
    for (int k = 0; k < 6; ++k) s += expf(t6[i*6+k]-m);
    lp0[i] = t6[i*6] - m - logf(s);
    int best = 0; float bv = t6[i*6];
    for (int k = 1; k < 6; ++k) if (t6[i*6+k] > bv) { bv = t6[i*6+k]; best = k; }
    amax[i] = best;
    float rsum = 0.0f;
    for (int q = 0; q < 512; ++q) rsum += h2tW[(size_t)i*512 + q];
    rs[i] = rsum;
  }
  __syncthreads();
  if (i == 0) {
    int dd = 4;                       // START
    for (int t = 0; t < 1024; ++t) { cseq[t] = lp0[dd]; dd = amax[dd]; }
  }
}

// ---------------- final output: out[t][k] = c_t * rowsum[k] + b[k] ----------------
__global__ __launch_bounds__(256)
void final_out(const float* __restrict__ cseq, const float* __restrict__ rs,
               const float* __restrict__ h2tb, float* __restrict__ outp)
{
  int idx = blockIdx.x*256 + threadIdx.x;
  if (idx < 6144) {
    int t = idx/6, k = idx - 6*t;
    outp[idx] = cseq[t]*rs[k] + h2tb[k];
  }
}

extern "C" void kernel_launch(void* const* d_in, const int* in_sizes, int n_in,
                              void* d_out, int out_size, void* d_ws, size_t ws_size,
                              hipStream_t stream)
{
  const int*   x     = (const int*)  d_in[0];
  const float* emb   = (const float*)d_in[1];
  const float* Wih0f = (const float*)d_in[2];
  const float* Whh0f = (const float*)d_in[3];
  const float* bih0f = (const float*)d_in[4];
  const float* bhh0f = (const float*)d_in[5];
  const float* Wih0b = (const float*)d_in[6];
  const float* Whh0b = (const float*)d_in[7];
  const float* bih0b = (const float*)d_in[8];
  const float* bhh0b = (const float*)d_in[9];
  const float* Wih1f = (const float*)d_in[10];
  const float* Whh1f = (const float*)d_in[11];
  const float* bih1f = (const float*)d_in[12];
  const float* bhh1f = (const float*)d_in[13];
  const float* Wih1b = (const float*)d_in[14];
  const float* Whh1b = (const float*)d_in[15];
  const float* bih1b = (const float*)d_in[16];
  const float* bhh1b = (const float*)d_in[17];
  const float* eh0   = (const float*)d_in[18];
  const float* deemb = (const float*)d_in[19];
  const float* attnW = (const float*)d_in[20];
  const float* attnb = (const float*)d_in[21];
  const float* combW = (const float*)d_in[22];
  const float* combb = (const float*)d_in[23];
  const float* deWih = (const float*)d_in[24];
  const float* deWhh = (const float*)d_in[25];
  const float* debih = (const float*)d_in[26];
  const float* debhh = (const float*)d_in[27];
  const float* h2tW  = (const float*)d_in[28];
  const float* h2tb  = (const float*)d_in[29];
  float* out = (float*)d_out;

  float* ws   = (float*)d_ws;
  float* G    = ws;                         // 1024*1536 (shared by layer0/layer1 gi)
  float* o0   = G    + (size_t)1024*1536;   // 1024*512
  float* hcat = o0   + (size_t)1024*512;    // 1024*512
  float* eout = hcat + (size_t)1024*512;    // 1024*512
  float* dh   = eout + (size_t)1024*512;    // 512
  float* atl  = dh   + 512;                 // 6*1024
  float* aw   = atl  + 6*1024;              // 6*1024
  float* ctx  = aw   + 6*1024;              // 6*512
  float* ob   = ctx  + 6*512;               // 6*512
  float* gid  = ob   + 6*512;               // 6*1536
  float* ghd  = gid  + 6*1536;              // 1536
  float* cseq = ghd  + 1536;                // 1024
  float* rs   = cseq + 1024;                // 6

  // ---- encoder ----
  gi_gemm<true, 256><<<dim3(16,24), 256, 0, stream>>>(nullptr, x, emb,
      Wih0f, Wih0b, bih0f, bih0b, G);
  enc_recur<0><<<2, 1024, 0, stream>>>(G, Whh0f, Whh0b, bhh0f, bhh0b, eh0, o0, dh);
  gi_gemm<false, 512><<<dim3(16,24), 256, 0, stream>>>(o0, nullptr, nullptr,
      Wih1f, Wih1b, bih1f, bih1b, G);
  enc_recur<1><<<2, 1024, 0, stream>>>(G, Whh1f, Whh1b, bhh1f, bhh1b, eh0, hcat, dh);
  row_logsoftmax<<<1024, 256, 0, stream>>>(hcat, eout);

  // ---- decoder: only 6 distinct states (dh is constant in the reference) ----
  matvec6<0><<<dim3(6,64), 256, 0, stream>>>(attnW, attnb, deemb, 512, 512,
      dh, 0, 512, 1024, atl);
  softmax6<<<6, 256, 0, stream>>>(atl, aw);
  ctx_kernel<<<6, 256, 0, stream>>>(aw, eout, ctx);
  matvec6<1><<<dim3(6,32), 256, 0, stream>>>(combW, combb, deemb, 512, 512,
      ctx, 512, 512, 512, ob);
  matvec6<0><<<dim3(6,96), 256, 0, stream>>>(deWih, debih, ob, 512, 512,
      nullptr, 0, 0, 1536, gid);
  matvec6<0><<<dim3(1,96), 256, 0, stream>>>(deWhh, debhh, dh, 0, 512,
      nullptr, 0, 0, 1536, ghd);
  dec_final<<<1, 512, 0, stream>>>(gid, ghd, dh, h2tW, h2tb, cseq, rs);
  final_out<<<24, 256, 0, stream>>>(cseq, rs, h2tb, out);
}

// Round 5
// 2721.586 us; speedup vs baseline: 1.3011x; 1.3011x over previous
//
#include <hip/hip_runtime.h>
#include <math.h>

typedef _Float16 h2 __attribute__((ext_vector_type(2)));
typedef _Float16 h8 __attribute__((ext_vector_type(8)));

__device__ __forceinline__ float sigmf_(float x){ return 1.0f/(1.0f + expf(-x)); }

// ---------------- P1/P3: C[1024][1536] = A[1024][K] @ [Wf;Wb]^T + [bf;bb] ----
template<bool GATHER, int K>
__global__ __launch_bounds__(256)
void gi_gemm(const float* __restrict__ A, const int* __restrict__ xids,
             const float* __restrict__ emb,
             const float* __restrict__ Wf, const float* __restrict__ Wb,
             const float* __restrict__ bf, const float* __restrict__ bb,
             float* __restrict__ C)
{
  __shared__ float As[64][17];
  __shared__ float Bs[64][17];
  __shared__ int xs[64];
  const int tid = threadIdx.x;
  const int m0 = blockIdx.x*64, n0 = blockIdx.y*64;
  if (GATHER && tid < 64) xs[tid] = xids[m0+tid];
  __syncthreads();
  const int tx = tid & 15, ty = tid >> 4;
  float acc[4][4] = {};
  for (int kc = 0; kc < K; kc += 16) {
#pragma unroll
    for (int p = 0; p < 4; ++p) {
      int r = ty + 16*p;
      float av;
      if (GATHER) av = emb[(size_t)xs[r]*K + kc + tx];
      else        av = A[(size_t)(m0+r)*K + kc + tx];
      As[r][tx] = av;
      int cn = n0 + r;
      float bv = (cn < 768) ? Wf[(size_t)cn*K + kc + tx]
                            : Wb[(size_t)(cn-768)*K + kc + tx];
      Bs[r][tx] = bv;
    }
    __syncthreads();
#pragma unroll
    for (int kk = 0; kk < 16; ++kk) {
      float a0=As[ty*4+0][kk], a1=As[ty*4+1][kk], a2=As[ty*4+2][kk], a3=As[ty*4+3][kk];
      float b0=Bs[tx*4+0][kk], b1=Bs[tx*4+1][kk], b2=Bs[tx*4+2][kk], b3=Bs[tx*4+3][kk];
      acc[0][0]+=a0*b0; acc[0][1]+=a0*b1; acc[0][2]+=a0*b2; acc[0][3]+=a0*b3;
      acc[1][0]+=a1*b0; acc[1][1]+=a1*b1; acc[1][2]+=a1*b2; acc[1][3]+=a1*b3;
      acc[2][0]+=a2*b0; acc[2][1]+=a2*b1; acc[2][2]+=a2*b2; acc[2][3]+=a2*b3;
      acc[3][0]+=a3*b0; acc[3][1]+=a3*b1; acc[3][2]+=a3*b2; acc[3][3]+=a3*b3;
    }
    __syncthreads();
  }
#pragma unroll
  for (int i=0;i<4;++i)
#pragma unroll
    for (int jj=0;jj<4;++jj) {
      int col = n0 + tx*4 + jj;
      float bias = (col<768)? bf[col] : bb[col-768];
      C[(size_t)(m0+ty*4+i)*1536 + col] = acc[i][jj] + bias;
    }
}

// ---------------- convert 4x Whh f32 -> f16, packed [cell][768][256] ----------
__global__ __launch_bounds__(256)
void wcvt(const float* __restrict__ W0, const float* __restrict__ W1,
          const float* __restrict__ W2, const float* __restrict__ W3,
          _Float16* __restrict__ O)
{
  const float* W = (blockIdx.y==0)?W0:(blockIdx.y==1)?W1:(blockIdx.y==2)?W2:W3;
  int i = (blockIdx.x*256 + threadIdx.x)*4;   // 196608 floats per matrix, grid.x=192
  float4 v = *(const float4*)(W + i);
  _Float16* o = O + (size_t)blockIdx.y*196608 + i;
  o[0]=(_Float16)v.x; o[1]=(_Float16)v.y; o[2]=(_Float16)v.z; o[3]=(_Float16)v.w;
}

// ---------------- Sequential GRU layer: 2 blocks (cell f/b) x 512 threads ----
// Thread (j,q): j = tid>>1 owns h-element j; q = tid&1 owns column half
// [q*128, q*128+128) of gate rows {j, j+256, j+512}. 192 weight VGPRs/thread.
// waves_per_eu(2,2) -> 256-reg budget; asm anchors make the loaded weights
// opaque so the allocator CANNOT rematerialize the loads inside the loop
// (the failure mode of rounds 1-3).
template<int LAYER>
__global__ __attribute__((amdgpu_flat_work_group_size(512,512), amdgpu_waves_per_eu(2,2)))
void enc_recur(const float* __restrict__ G,      // [1024][1536] gi (incl bih)
               const _Float16* __restrict__ W16, // [4][768][256] f16
               const float* __restrict__ bhhF, const float* __restrict__ bhhB,
               const float* __restrict__ eh0,   // [4][256]
               float* __restrict__ outbuf,      // [1024][512]
               float* __restrict__ dh)          // [512]
{
  const int c = blockIdx.x;       // 0 = f, 1 = b
  const int tid = threadIdx.x;
  const int j = tid >> 1, q = tid & 1;
  const _Float16* __restrict__ Wc = W16 + (size_t)(LAYER*2 + c)*196608;
  const float* __restrict__ bhh = c ? bhhB : bhhF;
  // chunk q at element offset q*136 (272 B): q=1 lands on banks 4-7, not 0-3
  __shared__ __align__(16) _Float16 hh[2][272];

  int w0i[64], w1i[64], w2i[64];
  {
    const int* r0 = (const int*)(Wc + (size_t)( j      )*256 + q*128);
    const int* r1 = (const int*)(Wc + (size_t)( j+256  )*256 + q*128);
    const int* r2 = (const int*)(Wc + (size_t)( j+512  )*256 + q*128);
#pragma unroll
    for (int k = 0; k < 64; ++k) { w0i[k] = r0[k]; w1i[k] = r1[k]; w2i[k] = r2[k]; }
  }
  // opaque anchors: values can no longer be rematerialized from memory
#pragma unroll
  for (int k = 0; k < 64; ++k) {
    asm("" : "+v"(w0i[k]));
    asm("" : "+v"(w1i[k]));
    asm("" : "+v"(w2i[k]));
  }
  // bias folded into q==0's accumulator so the pair-sum adds it exactly once
  const float br = q ? 0.0f : bhh[j];
  const float bz = q ? 0.0f : bhh[j+256];
  const float bn = q ? 0.0f : bhh[j+512];
  float h = eh0[(LAYER*2 + c)*256 + j];
  if (q == 0) hh[0][(j>>7)*136 + (j&127)] = (_Float16)h;
  __syncthreads();

  const float* Gn = G + c*768 + j;          // row-t per-thread base
  float gr = Gn[0], gz = Gn[256], gn_ = Gn[512];
  float* ob = outbuf + c*256 + j;

  for (int t = 0; t < 1024; ++t) {
    // prefetch next row's gi (t=1023 reads one row past G -> lands in the
    // adjacent ws buffer, value unused)
    Gn += 1536;
    float pr = Gn[0], pz = Gn[256], pn = Gn[512];

    float ar = br, az = bz, an = bn;
    const h8* __restrict__ hb = (const h8*)(hh[t & 1] + q*136);
#pragma unroll
    for (int kk = 0; kk < 16; ++kk) {
      h8 hv = hb[kk];
      h2 p0 = h2{hv[0],hv[1]}, p1 = h2{hv[2],hv[3]};
      h2 p2 = h2{hv[4],hv[5]}, p3 = h2{hv[6],hv[7]};
      ar = __builtin_amdgcn_fdot2(__builtin_bit_cast(h2, w0i[4*kk+0]), p0, ar, false);
      az = __builtin_amdgcn_fdot2(__builtin_bit_cast(h2, w1i[4*kk+0]), p0, az, false);
      an = __builtin_amdgcn_fdot2(__builtin_bit_cast(h2, w2i[4*kk+0]), p0, an, false);
      ar = __builtin_amdgcn_fdot2(__builtin_bit_cast(h2, w0i[4*kk+1]), p1, ar, false);
      az = __builtin_amdgcn_fdot2(__builtin_bit_cast(h2, w1i[4*kk+1]), p1, az, false);
      an = __builtin_amdgcn_fdot2(__builtin_bit_cast(h2, w2i[4*kk+1]), p1, an, false);
      ar = __builtin_amdgcn_fdot2(__builtin_bit_cast(h2, w0i[4*kk+2]), p2, ar, false);
      az = __builtin_amdgcn_fdot2(__builtin_bit_cast(h2, w1i[4*kk+2]), p2, az, false);
      an = __builtin_amdgcn_fdot2(__builtin_bit_cast(h2, w2i[4*kk+2]), p2, an, false);
      ar = __builtin_amdgcn_fdot2(__builtin_bit_cast(h2, w0i[4*kk+3]), p3, ar, false);
      az = __builtin_amdgcn_fdot2(__builtin_bit_cast(h2, w1i[4*kk+3]), p3, az, false);
      an = __builtin_amdgcn_fdot2(__builtin_bit_cast(h2, w2i[4*kk+3]), p3, an, false);
    }
    // combine the two column-halves (partners are adjacent lanes)
    ar += __shfl_xor(ar, 1);
    az += __shfl_xor(az, 1);
    an += __shfl_xor(an, 1);

    float r = sigmf_(gr + ar);
    float z = sigmf_(gz + az);
    float n = tanhf(gn_ + r*an);
    h = (1.0f - z)*n + z*h;
    if (q == 0) {
      ob[0] = h; ob += 512;
      hh[(t+1) & 1][(j>>7)*136 + (j&127)] = (_Float16)h;  // other buffer: no WAR
    }
    gr = pr; gz = pz; gn_ = pn;
    __syncthreads();                    // writes visible before next step reads
  }
  if (LAYER == 0 && c == 0 && q == 0) dh[j] = h;         // dh = concat(h0f, h1b)
  if (LAYER == 1 && c == 1 && q == 0) dh[256 + j] = h;
}

// ---------------- row-wise log_softmax over 512 features ----------------
__global__ __launch_bounds__(256)
void row_logsoftmax(const float* __restrict__ in, float* __restrict__ outp)
{
  const int t = blockIdx.x, i = threadIdx.x;
  __shared__ float red[256];
  float v0 = in[(size_t)t*512 + i], v1 = in[(size_t)t*512 + 256 + i];
  red[i] = fmaxf(v0, v1); __syncthreads();
  for (int s = 128; s > 0; s >>= 1) { if (i < s) red[i] = fmaxf(red[i], red[i+s]); __syncthreads(); }
  float m = red[0]; __syncthreads();
  red[i] = expf(v0-m) + expf(v1-m); __syncthreads();
  for (int s = 128; s > 0; s >>= 1) { if (i < s) red[i] += red[i+s]; __syncthreads(); }
  float ls = m + logf(red[0]);
  outp[(size_t)t*512 + i]       = v0 - ls;
  outp[(size_t)t*512 + 256 + i] = v1 - ls;
}

// ---------------- batched matvec over nd vectors: out[d][r] = act(W[r]·v_d + b[r])
template<int ACT>
__global__ __launch_bounds__(256)
void matvec6(const float* __restrict__ W, const float* __restrict__ bias,
             const float* __restrict__ Va, int strideA, int lenA,
             const float* __restrict__ Vb, int strideB, int lenB,
             int N, float* __restrict__ outp)
{
  const int d = blockIdx.x;
  const int K = lenA + lenB;
  __shared__ float v[1024];
  for (int k = threadIdx.x; k < K; k += 256)
    v[k] = (k < lenA) ? Va[(size_t)d*strideA + k] : Vb[(size_t)d*strideB + (k - lenA)];
  __syncthreads();
  const int tx = threadIdx.x & 15, ty = threadIdx.x >> 4;
  const int r = blockIdx.y*16 + ty;
  if (r < N) {                      // N is always a multiple of 16 here
    float acc = 0.0f;
    for (int k = tx; k < K; k += 16) acc += W[(size_t)r*K + k]*v[k];
    for (int m = 8; m >= 1; m >>= 1) acc += __shfl_xor(acc, m);
    if (tx == 0) {
      acc += bias[r];
      if (ACT == 1) acc = fmaxf(acc, 0.0f);
      outp[(size_t)d*N + r] = acc;
    }
  }
}

// ---------------- softmax over 1024 logits, 6 rows ----------------
__global__ __launch_bounds__(256)
void softmax6(const float* __restrict__ lg, float* __restrict__ aw)
{
  const int d = blockIdx.x, i = threadIdx.x;
  __shared__ float red[256];
  float v[4];
#pragma unroll
  for (int p = 0; p < 4; ++p) v[p] = lg[(size_t)d*1024 + i + 256*p];
  float m = fmaxf(fmaxf(v[0],v[1]), fmaxf(v[2],v[3]));
  red[i] = m; __syncthreads();
  for (int s = 128; s > 0; s >>= 1) { if (i < s) red[i] = fmaxf(red[i], red[i+s]); __syncthreads(); }
  m = red[0]; __syncthreads();
  float e[4]; float sl = 0.0f;
#pragma unroll
  for (int p = 0; p < 4; ++p) { e[p] = expf(v[p]-m); sl += e[p]; }
  red[i] = sl; __syncthreads();
  for (int s = 128; s > 0; s >>= 1) { if (i < s) red[i] += red[i+s]; __syncthreads(); }
  float inv = 1.0f/red[0];
#pragma unroll
  for (int p = 0; p < 4; ++p) aw[(size_t)d*1024 + i + 256*p] = e[p]*inv;
}

// ---------------- ctx[d] = aw[d] @ eoutputs  ([1024]·[1024,512]) ----------------
__global__ __launch_bounds__(256)
void ctx_kernel(const float* __restrict__ aw, const float* __restrict__ eout,
                float* __restrict__ ctx)
{
  const int d = blockIdx.x, c = threadIdx.x;
  __shared__ float a[1024];
  for (int m = c; m < 1024; m += 256) a[m] = aw[(size_t)d*1024 + m];
  __syncthreads();
  float s0 = 0.0f, s1 = 0.0f;
  for (int m = 0; m < 1024; ++m) {
    float am = a[m];
    s0 += am*eout[(size_t)m*512 + c];
    s1 += am*eout[(size_t)m*512 + 256 + c];
  }
  ctx[(size_t)d*512 + c] = s0;
  ctx[(size_t)d*512 + 256 + c] = s1;
}

// ---------------- decoder tail: GRU combine, logits, argmax-chain ----------------
__global__ __launch_bounds__(512)
void dec_final(const float* __restrict__ gidec, const float* __restrict__ ghdec,
               const float* __restrict__ dh, const float* __restrict__ h2tW,
               const float* __restrict__ h2tb,
               float* __restrict__ cseq, float* __restrict__ rs)
{
  __shared__ float hn[6][512];
  __shared__ float t6[36];
  __shared__ float lp0[6];
  __shared__ int amax[6];
  const int i = threadIdx.x;
  for (int d = 0; d < 6; ++d) {
    float r = sigmf_(gidec[(size_t)d*1536 + i]        + ghdec[i]);
    float z = sigmf_(gidec[(size_t)d*1536 + 512 + i]  + ghdec[512 + i]);
    float n = tanhf (gidec[(size_t)d*1536 + 1024 + i] + r*ghdec[1024 + i]);
    hn[d][i] = (1.0f - z)*n + z*dh[i];
  }
  __syncthreads();
  if (i < 36) {
    int d = i/6, k = i%6;
    float acc = h2tb[k];
    for (int q = 0; q < 512; ++q) acc += h2tW[(size_t)k*512 + q]*hn[d][q];
    t6[i] = acc;
  }
  __syncthreads();
  if (i < 6) {
    float m = t6[i*6];
    for (int k = 1; k < 6; ++k) m = fmaxf(m, t6[i*6+k]);
    float s = 0.0f;
    for (int k = 0; k < 6; ++k) s += expf(t6[i*6+k]-m);
    lp0[i] = t6[i*6] - m - logf(s);
    int best = 0; float bv = t6[i*6];
    for (int k = 1; k < 6; ++k) if (t6[i*6+k] > bv) { bv = t6[i*6+k]; best = k; }
    amax[i] = best;
    float rsum = 0.0f;
    for (int q = 0; q < 512; ++q) rsum += h2tW[(size_t)i*512 + q];
    rs[i] = rsum;
  }
  __syncthreads();
  if (i == 0) {
    int dd = 4;                       // START
    for (int t = 0; t < 1024; ++t) { cseq[t] = lp0[dd]; dd = amax[dd]; }
  }
}

// ---------------- final output: out[t][k] = c_t * rowsum[k] + b[k] ----------------
__global__ __launch_bounds__(256)
void final_out(const float* __restrict__ cseq, const float* __restrict__ rs,
               const float* __restrict__ h2tb, float* __restrict__ outp)
{
  int idx = blockIdx.x*256 + threadIdx.x;
  if (idx < 6144) {
    int t = idx/6, k = idx - 6*t;
    outp[idx] = cseq[t]*rs[k] + h2tb[k];
  }
}

extern "C" void kernel_launch(void* const* d_in, const int* in_sizes, int n_in,
                              void* d_out, int out_size, void* d_ws, size_t ws_size,
                              hipStream_t stream)
{
  const int*   x     = (const int*)  d_in[0];
  const float* emb   = (const float*)d_in[1];
  const float* Wih0f = (const float*)d_in[2];
  const float* Whh0f = (const float*)d_in[3];
  const float* bih0f = (const float*)d_in[4];
  const float* bhh0f = (const float*)d_in[5];
  const float* Wih0b = (const float*)d_in[6];
  const float* Whh0b = (const float*)d_in[7];
  const float* bih0b = (const float*)d_in[8];
  const float* bhh0b = (const float*)d_in[9];
  const float* Wih1f = (const float*)d_in[10];
  const float* Whh1f = (const float*)d_in[11];
  const float* bih1f = (const float*)d_in[12];
  const float* bhh1f = (const float*)d_in[13];
  const float* Wih1b = (const float*)d_in[14];
  const float* Whh1b = (const float*)d_in[15];
  const float* bih1b = (const float*)d_in[16];
  const float* bhh1b = (const float*)d_in[17];
  const float* eh0   = (const float*)d_in[18];
  const float* deemb = (const float*)d_in[19];
  const float* attnW = (const float*)d_in[20];
  const float* attnb = (const float*)d_in[21];
  const float* combW = (const float*)d_in[22];
  const float* combb = (const float*)d_in[23];
  const float* deWih = (const float*)d_in[24];
  const float* deWhh = (const float*)d_in[25];
  const float* debih = (const float*)d_in[26];
  const float* debhh = (const float*)d_in[27];
  const float* h2tW  = (const float*)d_in[28];
  const float* h2tb  = (const float*)d_in[29];
  float* out = (float*)d_out;

  float* ws   = (float*)d_ws;
  float* G    = ws;                         // 1024*1536 (shared by layer0/layer1 gi)
  float* o0   = G    + (size_t)1024*1536;   // 1024*512
  float* hcat = o0   + (size_t)1024*512;    // 1024*512
  float* eout = hcat + (size_t)1024*512;    // 1024*512
  float* dh   = eout + (size_t)1024*512;    // 512
  float* atl  = dh   + 512;                 // 6*1024
  float* aw   = atl  + 6*1024;              // 6*1024
  float* ctx  = aw   + 6*1024;              // 6*512
  float* ob   = ctx  + 6*512;               // 6*512
  float* gid  = ob   + 6*512;               // 6*1536
  float* ghd  = gid  + 6*1536;              // 1536
  float* cseq = ghd  + 1536;                // 1024
  float* rs   = cseq + 1024;                // 6
  // W16 aliases eout: last use (enc_recur<1>) precedes eout's first write
  // (row_logsoftmax) on the same stream. 4*196608 f16 = 393216 floats < 524288.
  _Float16* W16 = (_Float16*)eout;

  // ---- encoder ----
  wcvt<<<dim3(192,4), 256, 0, stream>>>(Whh0f, Whh0b, Whh1f, Whh1b, W16);
  gi_gemm<true, 256><<<dim3(16,24), 256, 0, stream>>>(nullptr, x, emb,
      Wih0f, Wih0b, bih0f, bih0b, G);
  enc_recur<0><<<2, 512, 0, stream>>>(G, W16, bhh0f, bhh0b, eh0, o0, dh);
  gi_gemm<false, 512><<<dim3(16,24), 256, 0, stream>>>(o0, nullptr, nullptr,
      Wih1f, Wih1b, bih1f, bih1b, G);
  enc_recur<1><<<2, 512, 0, stream>>>(G, W16, bhh1f, bhh1b, eh0, hcat, dh);
  row_logsoftmax<<<1024, 256, 0, stream>>>(hcat, eout);

  // ---- decoder: only 6 distinct states (dh is constant in the reference) ----
  matvec6<0><<<dim3(6,64), 256, 0, stream>>>(attnW, attnb, deemb, 512, 512,
      dh, 0, 512, 1024, atl);
  softmax6<<<6, 256, 0, stream>>>(atl, aw);
  ctx_kernel<<<6, 256, 0, stream>>>(aw, eout, ctx);
  matvec6<1><<<dim3(6,32), 256, 0, stream>>>(combW, combb, deemb, 512, 512,
      ctx, 512, 512, 512, ob);
  matvec6<0><<<dim3(6,96), 256, 0, stream>>>(deWih, debih, ob, 512, 512,
      nullptr, 0, 0, 1536, gid);
  matvec6<0><<<dim3(1,96), 256, 0, stream>>>(deWhh, debhh, dh, 0, 512,
      nullptr, 0, 0, 1536, ghd);
  dec_final<<<1, 512, 0, stream>>>(gid, ghd, dh, h2tW, h2tb, cseq, rs);
  final_out<<<24, 256, 0, stream>>>(cseq, rs, h2tb, out);
}

// Round 6
// 2720.110 us; speedup vs baseline: 1.3018x; 1.0005x over previous
//
#include <hip/hip_runtime.h>
#include <math.h>

typedef _Float16 h2 __attribute__((ext_vector_type(2)));
typedef _Float16 h8 __attribute__((ext_vector_type(8)));

__device__ __forceinline__ float sigmf_(float x){ return 1.0f/(1.0f + expf(-x)); }

// ---------------- P1/P3: C[1024][1536] = A[1024][K] @ [Wf;Wb]^T + [bf;bb] ----
template<bool GATHER, int K>
__global__ __launch_bounds__(256)
void gi_gemm(const float* __restrict__ A, const int* __restrict__ xids,
             const float* __restrict__ emb,
             const float* __restrict__ Wf, const float* __restrict__ Wb,
             const float* __restrict__ bf, const float* __restrict__ bb,
             float* __restrict__ C)
{
  __shared__ float As[64][17];
  __shared__ float Bs[64][17];
  __shared__ int xs[64];
  const int tid = threadIdx.x;
  const int m0 = blockIdx.x*64, n0 = blockIdx.y*64;
  if (GATHER && tid < 64) xs[tid] = xids[m0+tid];
  __syncthreads();
  const int tx = tid & 15, ty = tid >> 4;
  float acc[4][4] = {};
  for (int kc = 0; kc < K; kc += 16) {
#pragma unroll
    for (int p = 0; p < 4; ++p) {
      int r = ty + 16*p;
      float av;
      if (GATHER) av = emb[(size_t)xs[r]*K + kc + tx];
      else        av = A[(size_t)(m0+r)*K + kc + tx];
      As[r][tx] = av;
      int cn = n0 + r;
      float bv = (cn < 768) ? Wf[(size_t)cn*K + kc + tx]
                            : Wb[(size_t)(cn-768)*K + kc + tx];
      Bs[r][tx] = bv;
    }
    __syncthreads();
#pragma unroll
    for (int kk = 0; kk < 16; ++kk) {
      float a0=As[ty*4+0][kk], a1=As[ty*4+1][kk], a2=As[ty*4+2][kk], a3=As[ty*4+3][kk];
      float b0=Bs[tx*4+0][kk], b1=Bs[tx*4+1][kk], b2=Bs[tx*4+2][kk], b3=Bs[tx*4+3][kk];
      acc[0][0]+=a0*b0; acc[0][1]+=a0*b1; acc[0][2]+=a0*b2; acc[0][3]+=a0*b3;
      acc[1][0]+=a1*b0; acc[1][1]+=a1*b1; acc[1][2]+=a1*b2; acc[1][3]+=a1*b3;
      acc[2][0]+=a2*b0; acc[2][1]+=a2*b1; acc[2][2]+=a2*b2; acc[2][3]+=a2*b3;
      acc[3][0]+=a3*b0; acc[3][1]+=a3*b1; acc[3][2]+=a3*b2; acc[3][3]+=a3*b3;
    }
    __syncthreads();
  }
#pragma unroll
  for (int i=0;i<4;++i)
#pragma unroll
    for (int jj=0;jj<4;++jj) {
      int col = n0 + tx*4 + jj;
      float bias = (col<768)? bf[col] : bb[col-768];
      C[(size_t)(m0+ty*4+i)*1536 + col] = acc[i][jj] + bias;
    }
}

// ---------------- convert 4x Whh f32 -> f16, packed [cell][768][256] ----------
__global__ __launch_bounds__(256)
void wcvt(const float* __restrict__ W0, const float* __restrict__ W1,
          const float* __restrict__ W2, const float* __restrict__ W3,
          _Float16* __restrict__ O)
{
  const float* W = (blockIdx.y==0)?W0:(blockIdx.y==1)?W1:(blockIdx.y==2)?W2:W3;
  int i = (blockIdx.x*256 + threadIdx.x)*4;   // 196608 floats per matrix, grid.x=192
  float4 v = *(const float4*)(W + i);
  _Float16* o = O + (size_t)blockIdx.y*196608 + i;
  o[0]=(_Float16)v.x; o[1]=(_Float16)v.y; o[2]=(_Float16)v.z; o[3]=(_Float16)v.w;
}

// ---------------- Sequential GRU layer: 2 blocks (cell f/b) x 512 threads ----
// Thread (j,q): j = tid>>1 owns h-element j; q = tid&1 owns column half
// [q*128, q*128+128) of gate rows {j, j+256, j+512}. 192 weight VGPRs/thread.
// The 85KB LDS pad forces 1 block/CU so the SCHEDULER'S occupancy target is
// provably 2 waves/SIMD -> 256-reg budget -> no remat/spill of the weights
// (rounds 1-5: every attribute-based request was ignored; the heuristic
// targeted 4 waves/SIMD and sank or spilled the weight array).
template<int LAYER>
__global__ __attribute__((amdgpu_flat_work_group_size(512,512), amdgpu_waves_per_eu(2,2)))
void enc_recur(const float* __restrict__ G,      // [1024][1536] gi (incl bih)
               const _Float16* __restrict__ W16, // [4][768][256] f16
               const float* __restrict__ bhhF, const float* __restrict__ bhhB,
               const float* __restrict__ eh0,   // [4][256]
               float* __restrict__ outbuf,      // [1024][512]
               float* __restrict__ dh)          // [512]
{
  const int c = blockIdx.x;       // 0 = f, 1 = b
  const int tid = threadIdx.x;
  const int j = tid >> 1, q = tid & 1;
  const _Float16* __restrict__ Wc = W16 + (size_t)(LAYER*2 + c)*196608;
  const float* __restrict__ bhh = c ? bhhB : bhhF;
  // chunk q at element offset q*136 (272 B): q=1 lands on banks 4-7, not 0-3
  __shared__ __align__(16) _Float16 hh[2][272];
  // occupancy-forcing pad: 2 blocks cannot share a CU (2*86KB > 160KB)
  __shared__ unsigned long long pad_lds[10880];   // 85 KB
  if (blockIdx.x > 7) ((volatile unsigned long long*)pad_lds)[tid] = 0;  // never true; not provable

  int w0i[64], w1i[64], w2i[64];
  {
    const int* r0 = (const int*)(Wc + (size_t)( j      )*256 + q*128);
    const int* r1 = (const int*)(Wc + (size_t)( j+256  )*256 + q*128);
    const int* r2 = (const int*)(Wc + (size_t)( j+512  )*256 + q*128);
#pragma unroll
    for (int k = 0; k < 64; ++k) { w0i[k] = r0[k]; w1i[k] = r1[k]; w2i[k] = r2[k]; }
  }
  // opaque anchors: values can no longer be rematerialized from memory
#pragma unroll
  for (int k = 0; k < 64; ++k) {
    asm("" : "+v"(w0i[k]));
    asm("" : "+v"(w1i[k]));
    asm("" : "+v"(w2i[k]));
  }
  // bias folded into q==0's accumulator so the pair-sum adds it exactly once
  const float br = q ? 0.0f : bhh[j];
  const float bz = q ? 0.0f : bhh[j+256];
  const float bn = q ? 0.0f : bhh[j+512];
  float h = eh0[(LAYER*2 + c)*256 + j];
  if (q == 0) hh[0][(j>>7)*136 + (j&127)] = (_Float16)h;
  __syncthreads();

  const float* Gn = G + c*768 + j;          // row-t per-thread base
  float gr = Gn[0], gz = Gn[256], gn_ = Gn[512];
  float* ob = outbuf + c*256 + j;

  for (int t = 0; t < 1024; ++t) {
    // prefetch next row's gi (t=1023 reads one row past G -> lands in the
    // adjacent ws buffer, value unused)
    Gn += 1536;
    float pr = Gn[0], pz = Gn[256], pn = Gn[512];

    float ar = br, az = bz, an = bn;
    const h8* __restrict__ hb = (const h8*)(hh[t & 1] + q*136);
#pragma unroll
    for (int kk = 0; kk < 16; ++kk) {
      h8 hv = hb[kk];
      h2 p0 = h2{hv[0],hv[1]}, p1 = h2{hv[2],hv[3]};
      h2 p2 = h2{hv[4],hv[5]}, p3 = h2{hv[6],hv[7]};
      ar = __builtin_amdgcn_fdot2(__builtin_bit_cast(h2, w0i[4*kk+0]), p0, ar, false);
      az = __builtin_amdgcn_fdot2(__builtin_bit_cast(h2, w1i[4*kk+0]), p0, az, false);
      an = __builtin_amdgcn_fdot2(__builtin_bit_cast(h2, w2i[4*kk+0]), p0, an, false);
      ar = __builtin_amdgcn_fdot2(__builtin_bit_cast(h2, w0i[4*kk+1]), p1, ar, false);
      az = __builtin_amdgcn_fdot2(__builtin_bit_cast(h2, w1i[4*kk+1]), p1, az, false);
      an = __builtin_amdgcn_fdot2(__builtin_bit_cast(h2, w2i[4*kk+1]), p1, an, false);
      ar = __builtin_amdgcn_fdot2(__builtin_bit_cast(h2, w0i[4*kk+2]), p2, ar, false);
      az = __builtin_amdgcn_fdot2(__builtin_bit_cast(h2, w1i[4*kk+2]), p2, az, false);
      an = __builtin_amdgcn_fdot2(__builtin_bit_cast(h2, w2i[4*kk+2]), p2, an, false);
      ar = __builtin_amdgcn_fdot2(__builtin_bit_cast(h2, w0i[4*kk+3]), p3, ar, false);
      az = __builtin_amdgcn_fdot2(__builtin_bit_cast(h2, w1i[4*kk+3]), p3, az, false);
      an = __builtin_amdgcn_fdot2(__builtin_bit_cast(h2, w2i[4*kk+3]), p3, an, false);
    }
    // combine the two column-halves (partners are adjacent lanes)
    ar += __shfl_xor(ar, 1);
    az += __shfl_xor(az, 1);
    an += __shfl_xor(an, 1);

    float r = sigmf_(gr + ar);
    float z = sigmf_(gz + az);
    float n = tanhf(gn_ + r*an);
    h = (1.0f - z)*n + z*h;
    if (q == 0) {
      ob[0] = h; ob += 512;
      hh[(t+1) & 1][(j>>7)*136 + (j&127)] = (_Float16)h;  // other buffer: no WAR
    }
    gr = pr; gz = pz; gn_ = pn;
    __syncthreads();                    // writes visible before next step reads
  }
  if (LAYER == 0 && c == 0 && q == 0) dh[j] = h;         // dh = concat(h0f, h1b)
  if (LAYER == 1 && c == 1 && q == 0) dh[256 + j] = h;
}

// ---------------- row-wise log_softmax over 512 features ----------------
__global__ __launch_bounds__(256)
void row_logsoftmax(const float* __restrict__ in, float* __restrict__ outp)
{
  const int t = blockIdx.x, i = threadIdx.x;
  __shared__ float red[256];
  float v0 = in[(size_t)t*512 + i], v1 = in[(size_t)t*512 + 256 + i];
  red[i] = fmaxf(v0, v1); __syncthreads();
  for (int s = 128; s > 0; s >>= 1) { if (i < s) red[i] = fmaxf(red[i], red[i+s]); __syncthreads(); }
  float m = red[0]; __syncthreads();
  red[i] = expf(v0-m) + expf(v1-m); __syncthreads();
  for (int s = 128; s > 0; s >>= 1) { if (i < s) red[i] += red[i+s]; __syncthreads(); }
  float ls = m + logf(red[0]);
  outp[(size_t)t*512 + i]       = v0 - ls;
  outp[(size_t)t*512 + 256 + i] = v1 - ls;
}

// ---------------- batched matvec over nd vectors: out[d][r] = act(W[r]·v_d + b[r])
template<int ACT>
__global__ __launch_bounds__(256)
void matvec6(const float* __restrict__ W, const float* __restrict__ bias,
             const float* __restrict__ Va, int strideA, int lenA,
             const float* __restrict__ Vb, int strideB, int lenB,
             int N, float* __restrict__ outp)
{
  const int d = blockIdx.x;
  const int K = lenA + lenB;
  __shared__ float v[1024];
  for (int k = threadIdx.x; k < K; k += 256)
    v[k] = (k < lenA) ? Va[(size_t)d*strideA + k] : Vb[(size_t)d*strideB + (k - lenA)];
  __syncthreads();
  const int tx = threadIdx.x & 15, ty = threadIdx.x >> 4;
  const int r = blockIdx.y*16 + ty;
  if (r < N) {                      // N is always a multiple of 16 here
    float acc = 0.0f;
    for (int k = tx; k < K; k += 16) acc += W[(size_t)r*K + k]*v[k];
    for (int m = 8; m >= 1; m >>= 1) acc += __shfl_xor(acc, m);
    if (tx == 0) {
      acc += bias[r];
      if (ACT == 1) acc = fmaxf(acc, 0.0f);
      outp[(size_t)d*N + r] = acc;
    }
  }
}

// ---------------- softmax over 1024 logits, 6 rows ----------------
__global__ __launch_bounds__(256)
void softmax6(const float* __restrict__ lg, float* __restrict__ aw)
{
  const int d = blockIdx.x, i = threadIdx.x;
  __shared__ float red[256];
  float v[4];
#pragma unroll
  for (int p = 0; p < 4; ++p) v[p] = lg[(size_t)d*1024 + i + 256*p];
  float m = fmaxf(fmaxf(v[0],v[1]), fmaxf(v[2],v[3]));
  red[i] = m; __syncthreads();
  for (int s = 128; s > 0; s >>= 1) { if (i < s) red[i] = fmaxf(red[i], red[i+s]); __syncthreads(); }
  m = red[0]; __syncthreads();
  float e[4]; float sl = 0.0f;
#pragma unroll
  for (int p = 0; p < 4; ++p) { e[p] = expf(v[p]-m); sl += e[p]; }
  red[i] = sl; __syncthreads();
  for (int s = 128; s > 0; s >>= 1) { if (i < s) red[i] += red[i+s]; __syncthreads(); }
  float inv = 1.0f/red[0];
#pragma unroll
  for (int p = 0; p < 4; ++p) aw[(size_t)d*1024 + i + 256*p] = e[p]*inv;
}

// ---------------- ctx[d] = aw[d] @ eoutputs  ([1024]·[1024,512]) ----------------
__global__ __launch_bounds__(256)
void ctx_kernel(const float* __restrict__ aw, const float* __restrict__ eout,
                float* __restrict__ ctx)
{
  const int d = blockIdx.x, c = threadIdx.x;
  __shared__ float a[1024];
  for (int m = c; m < 1024; m += 256) a[m] = aw[(size_t)d*1024 + m];
  __syncthreads();
  float s0 = 0.0f, s1 = 0.0f;
  for (int m = 0; m < 1024; ++m) {
    float am = a[m];
    s0 += am*eout[(size_t)m*512 + c];
    s1 += am*eout[(size_t)m*512 + 256 + c];
  }
  ctx[(size_t)d*512 + c] = s0;
  ctx[(size_t)d*512 + 256 + c] = s1;
}

// ---------------- decoder tail: GRU combine, logits, argmax-chain ----------------
__global__ __launch_bounds__(512)
void dec_final(const float* __restrict__ gidec, const float* __restrict__ ghdec,
               const float* __restrict__ dh, const float* __restrict__ h2tW,
               const float* __restrict__ h2tb,
               float* __restrict__ cseq, float* __restrict__ rs)
{
  __shared__ float hn[6][512];
  __shared__ float t6[36];
  __shared__ float lp0[6];
  __shared__ int amax[6];
  const int i = threadIdx.x;
  for (int d = 0; d < 6; ++d) {
    float r = sigmf_(gidec[(size_t)d*1536 + i]        + ghdec[i]);
    float z = sigmf_(gidec[(size_t)d*1536 + 512 + i]  + ghdec[512 + i]);
    float n = tanhf (gidec[(size_t)d*1536 + 1024 + i] + r*ghdec[1024 + i]);
    hn[d][i] = (1.0f - z)*n + z*dh[i];
  }
  __syncthreads();
  if (i < 36) {
    int d = i/6, k = i%6;
    float acc = h2tb[k];
    for (int q = 0; q < 512; ++q) acc += h2tW[(size_t)k*512 + q]*hn[d][q];
    t6[i] = acc;
  }
  __syncthreads();
  if (i < 6) {
    float m = t6[i*6];
    for (int k = 1; k < 6; ++k) m = fmaxf(m, t6[i*6+k]);
    float s = 0.0f;
    for (int k = 0; k < 6; ++k) s += expf(t6[i*6+k]-m);
    lp0[i] = t6[i*6] - m - logf(s);
    int best = 0; float bv = t6[i*6];
    for (int k = 1; k < 6; ++k) if (t6[i*6+k] > bv) { bv = t6[i*6+k]; best = k; }
    amax[i] = best;
    float rsum = 0.0f;
    for (int q = 0; q < 512; ++q) rsum += h2tW[(size_t)i*512 + q];
    rs[i] = rsum;
  }
  __syncthreads();
  if (i == 0) {
    int dd = 4;                       // START
    for (int t = 0; t < 1024; ++t) { cseq[t] = lp0[dd]; dd = amax[dd]; }
  }
}

// ---------------- final output: out[t][k] = c_t * rowsum[k] + b[k] ----------------
__global__ __launch_bounds__(256)
void final_out(const float* __restrict__ cseq, const float* __restrict__ rs,
               const float* __restrict__ h2tb, float* __restrict__ outp)
{
  int idx = blockIdx.x*256 + threadIdx.x;
  if (idx < 6144) {
    int t = idx/6, k = idx - 6*t;
    outp[idx] = cseq[t]*rs[k] + h2tb[k];
  }
}

extern "C" void kernel_launch(void* const* d_in, const int* in_sizes, int n_in,
                              void* d_out, int out_size, void* d_ws, size_t ws_size,
                              hipStream_t stream)
{
  const int*   x     = (const int*)  d_in[0];
  const float* emb   = (const float*)d_in[1];
  const float* Wih0f = (const float*)d_in[2];
  const float* Whh0f = (const float*)d_in[3];
  const float* bih0f = (const float*)d_in[4];
  const float* bhh0f = (const float*)d_in[5];
  const float* Wih0b = (const float*)d_in[6];
  const float* Whh0b = (const float*)d_in[7];
  const float* bih0b = (const float*)d_in[8];
  const float* bhh0b = (const float*)d_in[9];
  const float* Wih1f = (const float*)d_in[10];
  const float* Whh1f = (const float*)d_in[11];
  const float* bih1f = (const float*)d_in[12];
  const float* bhh1f = (const float*)d_in[13];
  const float* Wih1b = (const float*)d_in[14];
  const float* Whh1b = (const float*)d_in[15];
  const float* bih1b = (const float*)d_in[16];
  const float* bhh1b = (const float*)d_in[17];
  const float* eh0   = (const float*)d_in[18];
  const float* deemb = (const float*)d_in[19];
  const float* attnW = (const float*)d_in[20];
  const float* attnb = (const float*)d_in[21];
  const float* combW = (const float*)d_in[22];
  const float* combb = (const float*)d_in[23];
  const float* deWih = (const float*)d_in[24];
  const float* deWhh = (const float*)d_in[25];
  const float* debih = (const float*)d_in[26];
  const float* debhh = (const float*)d_in[27];
  const float* h2tW  = (const float*)d_in[28];
  const float* h2tb  = (const float*)d_in[29];
  float* out = (float*)d_out;

  float* ws   = (float*)d_ws;
  float* G    = ws;                         // 1024*1536 (shared by layer0/layer1 gi)
  float* o0   = G    + (size_t)1024*1536;   // 1024*512
  float* hcat = o0   + (size_t)1024*512;    // 1024*512
  float* eout = hcat + (size_t)1024*512;    // 1024*512
  float* dh   = eout + (size_t)1024*512;    // 512
  float* atl  = dh   + 512;                 // 6*1024
  float* aw   = atl  + 6*1024;              // 6*1024
  float* ctx  = aw   + 6*1024;              // 6*512
  float* ob   = ctx  + 6*512;               // 6*512
  float* gid  = ob   + 6*512;               // 6*1536
  float* ghd  = gid  + 6*1536;              // 1536
  float* cseq = ghd  + 1536;                // 1024
  float* rs   = cseq + 1024;                // 6
  // W16 aliases eout: last use (enc_recur<1>) precedes eout's first write
  // (row_logsoftmax) on the same stream. 4*196608 f16 = 393216 floats < 524288.
  _Float16* W16 = (_Float16*)eout;

  // ---- encoder ----
  wcvt<<<dim3(192,4), 256, 0, stream>>>(Whh0f, Whh0b, Whh1f, Whh1b, W16);
  gi_gemm<true, 256><<<dim3(16,24), 256, 0, stream>>>(nullptr, x, emb,
      Wih0f, Wih0b, bih0f, bih0b, G);
  enc_recur<0><<<2, 512, 0, stream>>>(G, W16, bhh0f, bhh0b, eh0, o0, dh);
  gi_gemm<false, 512><<<dim3(16,24), 256, 0, stream>>>(o0, nullptr, nullptr,
      Wih1f, Wih1b, bih1f, bih1b, G);
  enc_recur<1><<<2, 512, 0, stream>>>(G, W16, bhh1f, bhh1b, eh0, hcat, dh);
  row_logsoftmax<<<1024, 256, 0, stream>>>(hcat, eout);

  // ---- decoder: only 6 distinct states (dh is constant in the reference) ----
  matvec6<0><<<dim3(6,64), 256, 0, stream>>>(attnW, attnb, deemb, 512, 512,
      dh, 0, 512, 1024, atl);
  softmax6<<<6, 256, 0, stream>>>(atl, aw);
  ctx_kernel<<<6, 256, 0, stream>>>(aw, eout, ctx);
  matvec6<1><<<dim3(6,32), 256, 0, stream>>>(combW, combb, deemb, 512, 512,
      ctx, 512, 512, 512, ob);
  matvec6<0><<<dim3(6,96), 256, 0, stream>>>(deWih, debih, ob, 512, 512,
      nullptr, 0, 0, 1536, gid);
  matvec6<0><<<dim3(1,96), 256, 0, stream>>>(deWhh, debhh, dh, 0, 512,
      nullptr, 0, 0, 1536, ghd);
  dec_final<<<1, 512, 0, stream>>>(gid, ghd, dh, h2tW, h2tb, cseq, rs);
  final_out<<<24, 256, 0, stream>>>(cseq, rs, h2tb, out);
}